// Round 10
// baseline (31.840 us; speedup 1.0000x reference)
//
#include <hip/hip_runtime.h>

#define GRIDS 7
#define NCELL 49
#define NFEAT 25
#define CELLSZ 1225   // 49*25 floats per batch
#define BPB 16        // batches per block -> 1024 blocks at B=16384
#define MAXBOX 16

// Decomposition:
//   gather:   every cell contributes 0.5 * p_conf^2  (conf lane only)
//   correct:  each kept box's cell adds
//     f<2 : 5*(xo|yo - p)^2
//     f=2,3: 5*(sqrt(w|h) - sqrt(p))^2
//     f=4 : (1-p)^2 - 0.5*p^2     (replaces the gathered default)
//     f>=5: (onehot - p)^2
// SINGLE kernel. Cross-block reduction lessons:
//   R5: threadfence+ACQ_REL per block -> L2 writeback storms (91us).
//   R8: 2048 same-address relaxed atomics in a burst -> ~18us serialization.
// Here: distinct-address agent-scope partial stores (no serialization) +
// two-level counter tree (<=33 same-address increments total on any line) +
// vmcnt-completion ordering (R8's proven-correct trick, no cache maintenance).
// Root-last block reduces all partials in fixed order (deterministic).

__global__ __launch_bounds__(256) void yolo_onek(
    const float* __restrict__ pred, const float* __restrict__ bbox,
    float* __restrict__ partial, unsigned* __restrict__ gcnt,
    unsigned* __restrict__ root, float* __restrict__ out,
    int B, int nbox, int nblocks, int ngroups)
{
    __shared__ float  sBox[BPB * MAXBOX * 5];   // xo, yo, sqrt(w), sqrt(h), label
    __shared__ int    sOff[BPB * MAXBOX];       // element offset of box's cell in slab
    __shared__ int    sKeep[BPB * MAXBOX];
    __shared__ float  sRed[4];
    __shared__ double sRedD[256];
    __shared__ int    sLast;

    const int tid = threadIdx.x;
    const long long b0 = (long long)blockIdx.x * BPB;
    const int nb = min(BPB, B - (int)b0);
    const int nbx = nb * nbox;                  // <= 256
    const float* pb = pred + b0 * CELLSZ;

    // 0) Conf-lane gather ISSUE — first instructions, zero dependencies.
    const int ncells = nb * NCELL;
    float cf0 = 0.f, cf1 = 0.f, cf2 = 0.f, cf3 = 0.f;
    {
        int t0 = tid, t1 = tid + 256, t2 = tid + 512, t3 = tid + 768;
        if (t0 < ncells) {
            unsigned lb = ((unsigned)t0 * 2676u) >> 17;           // t/49
            cf0 = pb[lb * CELLSZ + ((unsigned)t0 - lb * 49u) * NFEAT + 4];
        }
        if (t1 < ncells) {
            unsigned lb = ((unsigned)t1 * 2676u) >> 17;
            cf1 = pb[lb * CELLSZ + ((unsigned)t1 - lb * 49u) * NFEAT + 4];
        }
        if (t2 < ncells) {
            unsigned lb = ((unsigned)t2 * 2676u) >> 17;
            cf2 = pb[lb * CELLSZ + ((unsigned)t2 - lb * 49u) * NFEAT + 4];
        }
        if (t3 < ncells) {
            unsigned lb = ((unsigned)t3 * 2676u) >> 17;
            cf3 = pb[lb * CELLSZ + ((unsigned)t3 - lb * 49u) * NFEAT + 4];
        }
    }

    // Preamble A: per-box derived values (f32 op order matches reference)
    if (tid < nbx) {
        const float* bx = bbox + (b0 * nbox + tid) * 5;
        float x1 = bx[0] / 448.f, y1 = bx[1] / 448.f;
        float x2 = bx[2] / 448.f, y2 = bx[3] / 448.f;
        float xc = (x1 + x2) * 0.5f, yc = (y1 + y2) * 0.5f;
        float w  = x2 - x1,          h  = y2 - y1;
        float xs = xc * (float)GRIDS, ys = yc * (float)GRIDS;
        float xg = floorf(xs), yg = floorf(ys);
        int lb = tid / nbox;
        int cell = (int)yg * GRIDS + (int)xg;
        sOff[tid] = lb * CELLSZ + cell * NFEAT;
        float* e = &sBox[tid * 5];
        e[0] = xs - xg; e[1] = ys - yg;
        e[2] = sqrtf(w); e[3] = sqrtf(h);
        e[4] = bx[4];
    }
    __syncthreads();

    // Preamble B: keep mask — first box claiming a cell (within its batch) wins.
    if (tid < nbx) {
        int lb = tid / nbox;
        int o  = sOff[tid];
        int k = 1;
        for (int j = lb * nbox; j < tid; ++j)
            if (sOff[j] == o) { k = 0; break; }
        sKeep[tid] = k;
    }
    __syncthreads();

    // 1) Correction gather ISSUE (hoisted): each 32-lane half-wave covers one
    //    box's 25 features.
    const int wid = tid >> 6, lane = tid & 63;
    const int f = lane & 31;
    const int cbase = wid * 2 + (lane >> 5);    // 0..7
    float gv[16];
    #pragma unroll
    for (int k = 0; k < 16; ++k) {
        int bi = cbase + 8 * k;
        bool v = (bi < nbx) && (f < NFEAT) && sKeep[bi];
        gv[k] = v ? pb[sOff[bi] + f] : 0.f;
    }

    // 2) Conf consume: 0.5*p^2
    float acc = 0.f;
    acc = fmaf(0.5f * cf0, cf0, acc);
    acc = fmaf(0.5f * cf1, cf1, acc);
    acc = fmaf(0.5f * cf2, cf2, acc);
    acc = fmaf(0.5f * cf3, cf3, acc);

    // 3) Correction consume
    #pragma unroll
    for (int k = 0; k < 16; ++k) {
        int bi = cbase + 8 * k;
        bool v = (bi < nbx) && (f < NFEAT) && sKeep[bi];
        if (v) {
            const float* e = &sBox[bi * 5];
            float p = gv[k];
            float term;
            if (f == 4) {
                float d = 1.f - p;
                term = fmaf(d, d, -0.5f * p * p);
            } else if (f < 4) {
                float q = (f >= 2) ? sqrtf(p) : p;
                float d = e[f] - q;
                term = 5.f * d * d;
            } else {
                float t = ((int)e[4] == f - 5) ? 1.f : 0.f;
                float d = t - p;
                term = d * d;
            }
            acc += term;
        }
    }
    // Safety tail: boxes beyond the hoisted window (never taken when nbx<=128)
    for (int bi = 128 + cbase; bi < nbx; bi += 8) {
        if (f < NFEAT && sKeep[bi]) {
            const float* e = &sBox[bi * 5];
            float p = pb[sOff[bi] + f];
            float term;
            if (f == 4) {
                float d = 1.f - p;
                term = fmaf(d, d, -0.5f * p * p);
            } else if (f < 4) {
                float q = (f >= 2) ? sqrtf(p) : p;
                float d = e[f] - q;
                term = 5.f * d * d;
            } else {
                float t = ((int)e[4] == f - 5) ? 1.f : 0.f;
                float d = t - p;
                term = d * d;
            }
            acc += term;
        }
    }

    // 4) Deterministic block reduction
    for (int off = 32; off; off >>= 1)
        acc += __shfl_down(acc, off, 64);
    if ((tid & 63) == 0) sRed[tid >> 6] = acc;
    __syncthreads();

    // 5) Fence-free, low-contention cross-block reduction.
    if (tid == 0) {
        float bsum = sRed[0] + sRed[1] + sRed[2] + sRed[3];
        // Distinct-address agent-scope store: performs at the coherent point,
        // no serialization, no cache maintenance.
        __hip_atomic_store(&partial[blockIdx.x], bsum, __ATOMIC_RELAXED,
                           __HIP_MEMORY_SCOPE_AGENT);
        asm volatile("s_waitcnt vmcnt(0)" ::: "memory");   // store performed
        int g = blockIdx.x >> 5;
        int gsz = min(32, nblocks - (g << 5));
        int last = 0;
        unsigned gp = __hip_atomic_fetch_add(&gcnt[g * 16], 1u, __ATOMIC_RELAXED,
                                             __HIP_MEMORY_SCOPE_AGENT);
        if ((int)gp == gsz - 1) {
            // gp's use ordered the gcnt add before this root add.
            unsigned rp = __hip_atomic_fetch_add(root, 1u, __ATOMIC_RELAXED,
                                                 __HIP_MEMORY_SCOPE_AGENT);
            last = ((int)rp == ngroups - 1);
        }
        sLast = last;
    }
    __syncthreads();

    // 6) Root-last block: all partial stores have performed at the coherent
    //    point (counter chain evidence); read them coherently, fixed order.
    if (sLast) {
        double a = 0.0;
        for (int j = tid; j < nblocks; j += 256)
            a += (double)__hip_atomic_load(&partial[j], __ATOMIC_RELAXED,
                                           __HIP_MEMORY_SCOPE_AGENT);
        sRedD[tid] = a;
        __syncthreads();
        for (int s = 128; s; s >>= 1) {
            if (tid < s) sRedD[tid] += sRedD[tid + s];
            __syncthreads();
        }
        if (tid == 0) out[0] = (float)(sRedD[0] / (double)B);
    }
}

extern "C" void kernel_launch(void* const* d_in, const int* in_sizes, int n_in,
                              void* d_out, int out_size, void* d_ws, size_t ws_size,
                              hipStream_t stream) {
    const float* pred = (const float*)d_in[0];
    const float* bbox = (const float*)d_in[1];
    int B = in_sizes[0] / CELLSZ;
    int nbox = in_sizes[1] / (B * 5);
    if (nbox > MAXBOX) nbox = MAXBOX;
    float* out = (float*)d_out;

    int nblocks = (B + BPB - 1) / BPB;      // 1024 at B=16384
    int ngroups = (nblocks + 31) / 32;      // 32  (supported up to 128)

    float* partial = (float*)d_ws;                                   // [nblocks]
    unsigned* gcnt = (unsigned*)((char*)d_ws + 65536);               // 64B-strided
    unsigned* root = (unsigned*)((char*)d_ws + 65536 + 128 * 64);

    hipMemsetAsync((char*)d_ws + 65536, 0, 128 * 64 + 64, stream);
    yolo_onek<<<nblocks, 256, 0, stream>>>(pred, bbox, partial, gcnt, root, out,
                                           B, nbox, nblocks, ngroups);
}

// Round 12
// 29.969 us; speedup vs baseline: 1.0625x; 1.0625x over previous
//
#include <hip/hip_runtime.h>

#define GRIDS 7
#define NCELL 49
#define NFEAT 25
#define CELLSZ 1225   // 49*25 floats per batch
#define BPB 16        // batches per block -> 1024 blocks at B=16384
#define MAXBOX 16

// Decomposition:
//   gather:   every cell contributes 0.5 * p_conf^2  (conf lane only — noobj
//             cells need nothing else; lines are fetched whole anyway)
//   correct:  each kept box's cell adds
//     f<2 : 5*(xo|yo - p)^2
//     f=2,3: 5*(sqrt(w|h) - sqrt(p))^2
//     f=4 : (1-p)^2 - 0.5*p^2     (replaces the gathered default)
//     f>=5: (onehot - p)^2
// Two kernels — FINAL STRUCTURE. In-kernel cross-block combining was tried
// four ways and lost every time on this chip:
//   R5  fences+ACQ_REL        -> L2 writeback storms, 91us
//   R8  1-address atomics     -> burst serialization, 45us
//   R10 counter tree + memset -> 31.8us (sync machinery > launch cost)
//   R11 init-free mod counter -> WRONG (trigger != last arrival w/ garbage init)

__global__ __launch_bounds__(256) void yolo_main(
    const float* __restrict__ pred, const float* __restrict__ bbox,
    float* __restrict__ partial, int B, int nbox)
{
    __shared__ float sBox[BPB * MAXBOX * 5];   // xo, yo, sqrt(w), sqrt(h), label
    __shared__ int   sOff[BPB * MAXBOX];       // element offset of box's cell in slab
    __shared__ int   sKeep[BPB * MAXBOX];
    __shared__ float sRed[4];

    const int tid = threadIdx.x;
    const long long b0 = (long long)blockIdx.x * BPB;
    const int nb = min(BPB, B - (int)b0);
    const int nbx = nb * nbox;                  // <= 256
    const float* pb = pred + b0 * CELLSZ;

    // 0) Conf-lane gather ISSUE — first instructions of the kernel, zero
    //    dependencies; all loads in flight while the preamble runs.
    const int ncells = nb * NCELL;
    float cf0 = 0.f, cf1 = 0.f, cf2 = 0.f, cf3 = 0.f;
    {
        int t0 = tid, t1 = tid + 256, t2 = tid + 512, t3 = tid + 768;
        if (t0 < ncells) {
            unsigned lb = ((unsigned)t0 * 2676u) >> 17;           // t/49
            cf0 = pb[lb * CELLSZ + ((unsigned)t0 - lb * 49u) * NFEAT + 4];
        }
        if (t1 < ncells) {
            unsigned lb = ((unsigned)t1 * 2676u) >> 17;
            cf1 = pb[lb * CELLSZ + ((unsigned)t1 - lb * 49u) * NFEAT + 4];
        }
        if (t2 < ncells) {
            unsigned lb = ((unsigned)t2 * 2676u) >> 17;
            cf2 = pb[lb * CELLSZ + ((unsigned)t2 - lb * 49u) * NFEAT + 4];
        }
        if (t3 < ncells) {
            unsigned lb = ((unsigned)t3 * 2676u) >> 17;
            cf3 = pb[lb * CELLSZ + ((unsigned)t3 - lb * 49u) * NFEAT + 4];
        }
    }

    // Preamble A: per-box derived values (f32 op order matches reference)
    if (tid < nbx) {
        const float* bx = bbox + (b0 * nbox + tid) * 5;
        float x1 = bx[0] / 448.f, y1 = bx[1] / 448.f;
        float x2 = bx[2] / 448.f, y2 = bx[3] / 448.f;
        float xc = (x1 + x2) * 0.5f, yc = (y1 + y2) * 0.5f;
        float w  = x2 - x1,          h  = y2 - y1;
        float xs = xc * (float)GRIDS, ys = yc * (float)GRIDS;
        float xg = floorf(xs), yg = floorf(ys);
        int lb = tid / nbox;
        int cell = (int)yg * GRIDS + (int)xg;
        sOff[tid] = lb * CELLSZ + cell * NFEAT;
        float* e = &sBox[tid * 5];
        e[0] = xs - xg; e[1] = ys - yg;
        e[2] = sqrtf(w); e[3] = sqrtf(h);
        e[4] = bx[4];
    }
    __syncthreads();

    // Preamble B: keep mask — first box claiming a cell (within its batch) wins.
    if (tid < nbx) {
        int lb = tid / nbox;
        int o  = sOff[tid];
        int k = 1;
        for (int j = lb * nbox; j < tid; ++j)
            if (sOff[j] == o) { k = 0; break; }
        sKeep[tid] = k;
    }
    __syncthreads();

    // 1) Correction gather ISSUE (hoisted): each 32-lane half-wave covers one
    //    box's 25 features; latency hides under the conf consume below.
    const int wid = tid >> 6, lane = tid & 63;
    const int f = lane & 31;
    const int cbase = wid * 2 + (lane >> 5);    // 0..7
    float gv[16];
    #pragma unroll
    for (int k = 0; k < 16; ++k) {
        int bi = cbase + 8 * k;
        bool v = (bi < nbx) && (f < NFEAT) && sKeep[bi];
        gv[k] = v ? pb[sOff[bi] + f] : 0.f;
    }

    // 2) Conf consume: 0.5*p^2
    float acc = 0.f;
    acc = fmaf(0.5f * cf0, cf0, acc);
    acc = fmaf(0.5f * cf1, cf1, acc);
    acc = fmaf(0.5f * cf2, cf2, acc);
    acc = fmaf(0.5f * cf3, cf3, acc);

    // 3) Correction consume
    #pragma unroll
    for (int k = 0; k < 16; ++k) {
        int bi = cbase + 8 * k;
        bool v = (bi < nbx) && (f < NFEAT) && sKeep[bi];
        if (v) {
            const float* e = &sBox[bi * 5];
            float p = gv[k];
            float term;
            if (f == 4) {
                float d = 1.f - p;
                term = fmaf(d, d, -0.5f * p * p);
            } else if (f < 4) {
                float q = (f >= 2) ? sqrtf(p) : p;
                float d = e[f] - q;
                term = 5.f * d * d;
            } else {
                float t = ((int)e[4] == f - 5) ? 1.f : 0.f;
                float d = t - p;
                term = d * d;
            }
            acc += term;
        }
    }
    // Safety tail: boxes beyond the hoisted window (never taken when nbx<=128)
    for (int bi = 128 + cbase; bi < nbx; bi += 8) {
        if (f < NFEAT && sKeep[bi]) {
            const float* e = &sBox[bi * 5];
            float p = pb[sOff[bi] + f];
            float term;
            if (f == 4) {
                float d = 1.f - p;
                term = fmaf(d, d, -0.5f * p * p);
            } else if (f < 4) {
                float q = (f >= 2) ? sqrtf(p) : p;
                float d = e[f] - q;
                term = 5.f * d * d;
            } else {
                float t = ((int)e[4] == f - 5) ? 1.f : 0.f;
                float d = t - p;
                term = d * d;
            }
            acc += term;
        }
    }

    // 4) Deterministic block reduction
    for (int off = 32; off; off >>= 1)
        acc += __shfl_down(acc, off, 64);
    if ((tid & 63) == 0) sRed[tid >> 6] = acc;
    __syncthreads();
    if (tid == 0)
        partial[blockIdx.x] = sRed[0] + sRed[1] + sRed[2] + sRed[3];
}

// Single-wave reduce: fixed-order per-lane double sums + butterfly shuffle
// (fixed tree) -> bit-deterministic, no __syncthreads.
__global__ __launch_bounds__(64) void yolo_reduce(
    const float* __restrict__ partial, int n, float* __restrict__ out, int B)
{
    const int lane = threadIdx.x;
    double a = 0.0;
    for (int j = lane; j < n; j += 64)
        a += (double)partial[j];
    for (int off = 32; off; off >>= 1)
        a += __shfl_xor(a, off, 64);
    if (lane == 0) out[0] = (float)(a / (double)B);
}

extern "C" void kernel_launch(void* const* d_in, const int* in_sizes, int n_in,
                              void* d_out, int out_size, void* d_ws, size_t ws_size,
                              hipStream_t stream) {
    const float* pred = (const float*)d_in[0];
    const float* bbox = (const float*)d_in[1];
    int B = in_sizes[0] / CELLSZ;
    int nbox = in_sizes[1] / (B * 5);
    if (nbox > MAXBOX) nbox = MAXBOX;
    float* out = (float*)d_out;
    float* partial = (float*)d_ws;

    int nblocks = (B + BPB - 1) / BPB;
    yolo_main<<<nblocks, 256, 0, stream>>>(pred, bbox, partial, B, nbox);
    yolo_reduce<<<1, 64, 0, stream>>>(partial, nblocks, out, B);
}

// Round 13
// 26.348 us; speedup vs baseline: 1.2084x; 1.1374x over previous
//
#include <hip/hip_runtime.h>

#define GRIDS 7
#define NCELL 49
#define NFEAT 25
#define CELLSZ 1225   // 49*25 floats per batch
#define BPB 16        // batches per block -> 1024 blocks at B=16384
#define MAXBOX 16

// Decomposition:
//   gather:   every cell contributes 0.5 * p_conf^2  (conf lane only)
//   correct:  each kept box's cell adds
//     f<2 : 5*(xo|yo - p)^2
//     f=2,3: 5*(sqrt(w|h) - sqrt(p))^2
//     f=4 : (1-p)^2 - 0.5*p^2     (replaces the gathered default)
//     f>=5: (onehot - p)^2
// Two kernels — FINAL (exact R9, the measured best at 26.3us).
// Structural dead ends, measured:
//   R5  fences+ACQ_REL          -> L2 writeback storms, 91us
//   R8  1-address atomics       -> burst serialization, 45us
//   R10 counter tree + memset   -> 31.8us (sync machinery > launch cost)
//   R11 init-free mod counter   -> WRONG (trigger != last arrival)
//   R12 single-wave reduce      -> 30us (tail kernel is latency-bound; keep
//                                  256 threads + float4 loads in flight)

__global__ __launch_bounds__(256) void yolo_main(
    const float* __restrict__ pred, const float* __restrict__ bbox,
    float* __restrict__ partial, int B, int nbox)
{
    __shared__ float sBox[BPB * MAXBOX * 5];   // xo, yo, sqrt(w), sqrt(h), label
    __shared__ int   sOff[BPB * MAXBOX];       // element offset of box's cell in slab
    __shared__ int   sKeep[BPB * MAXBOX];
    __shared__ float sRed[4];

    const int tid = threadIdx.x;
    const long long b0 = (long long)blockIdx.x * BPB;
    const int nb = min(BPB, B - (int)b0);
    const int nbx = nb * nbox;                  // <= 256
    const float* pb = pred + b0 * CELLSZ;

    // 0) Conf-lane gather ISSUE — first instructions, zero dependencies.
    const int ncells = nb * NCELL;
    float cf0 = 0.f, cf1 = 0.f, cf2 = 0.f, cf3 = 0.f;
    {
        int t0 = tid, t1 = tid + 256, t2 = tid + 512, t3 = tid + 768;
        if (t0 < ncells) {
            unsigned lb = ((unsigned)t0 * 2676u) >> 17;           // t/49
            cf0 = pb[lb * CELLSZ + ((unsigned)t0 - lb * 49u) * NFEAT + 4];
        }
        if (t1 < ncells) {
            unsigned lb = ((unsigned)t1 * 2676u) >> 17;
            cf1 = pb[lb * CELLSZ + ((unsigned)t1 - lb * 49u) * NFEAT + 4];
        }
        if (t2 < ncells) {
            unsigned lb = ((unsigned)t2 * 2676u) >> 17;
            cf2 = pb[lb * CELLSZ + ((unsigned)t2 - lb * 49u) * NFEAT + 4];
        }
        if (t3 < ncells) {
            unsigned lb = ((unsigned)t3 * 2676u) >> 17;
            cf3 = pb[lb * CELLSZ + ((unsigned)t3 - lb * 49u) * NFEAT + 4];
        }
    }

    // Preamble A: per-box derived values (f32 op order matches reference)
    if (tid < nbx) {
        const float* bx = bbox + (b0 * nbox + tid) * 5;
        float x1 = bx[0] / 448.f, y1 = bx[1] / 448.f;
        float x2 = bx[2] / 448.f, y2 = bx[3] / 448.f;
        float xc = (x1 + x2) * 0.5f, yc = (y1 + y2) * 0.5f;
        float w  = x2 - x1,          h  = y2 - y1;
        float xs = xc * (float)GRIDS, ys = yc * (float)GRIDS;
        float xg = floorf(xs), yg = floorf(ys);
        int lb = tid / nbox;
        int cell = (int)yg * GRIDS + (int)xg;
        sOff[tid] = lb * CELLSZ + cell * NFEAT;
        float* e = &sBox[tid * 5];
        e[0] = xs - xg; e[1] = ys - yg;
        e[2] = sqrtf(w); e[3] = sqrtf(h);
        e[4] = bx[4];
    }
    __syncthreads();

    // Preamble B: keep mask — first box claiming a cell (within its batch) wins.
    if (tid < nbx) {
        int lb = tid / nbox;
        int o  = sOff[tid];
        int k = 1;
        for (int j = lb * nbox; j < tid; ++j)
            if (sOff[j] == o) { k = 0; break; }
        sKeep[tid] = k;
    }
    __syncthreads();

    // 1) Correction gather ISSUE (hoisted): each 32-lane half-wave covers one
    //    box's 25 features.
    const int wid = tid >> 6, lane = tid & 63;
    const int f = lane & 31;
    const int cbase = wid * 2 + (lane >> 5);    // 0..7
    float gv[16];
    #pragma unroll
    for (int k = 0; k < 16; ++k) {
        int bi = cbase + 8 * k;
        bool v = (bi < nbx) && (f < NFEAT) && sKeep[bi];
        gv[k] = v ? pb[sOff[bi] + f] : 0.f;
    }

    // 2) Conf consume: 0.5*p^2
    float acc = 0.f;
    acc = fmaf(0.5f * cf0, cf0, acc);
    acc = fmaf(0.5f * cf1, cf1, acc);
    acc = fmaf(0.5f * cf2, cf2, acc);
    acc = fmaf(0.5f * cf3, cf3, acc);

    // 3) Correction consume
    #pragma unroll
    for (int k = 0; k < 16; ++k) {
        int bi = cbase + 8 * k;
        bool v = (bi < nbx) && (f < NFEAT) && sKeep[bi];
        if (v) {
            const float* e = &sBox[bi * 5];
            float p = gv[k];
            float term;
            if (f == 4) {
                float d = 1.f - p;
                term = fmaf(d, d, -0.5f * p * p);
            } else if (f < 4) {
                float q = (f >= 2) ? sqrtf(p) : p;
                float d = e[f] - q;
                term = 5.f * d * d;
            } else {
                float t = ((int)e[4] == f - 5) ? 1.f : 0.f;
                float d = t - p;
                term = d * d;
            }
            acc += term;
        }
    }
    // Safety tail: boxes beyond the hoisted window (never taken when nbx<=128)
    for (int bi = 128 + cbase; bi < nbx; bi += 8) {
        if (f < NFEAT && sKeep[bi]) {
            const float* e = &sBox[bi * 5];
            float p = pb[sOff[bi] + f];
            float term;
            if (f == 4) {
                float d = 1.f - p;
                term = fmaf(d, d, -0.5f * p * p);
            } else if (f < 4) {
                float q = (f >= 2) ? sqrtf(p) : p;
                float d = e[f] - q;
                term = 5.f * d * d;
            } else {
                float t = ((int)e[4] == f - 5) ? 1.f : 0.f;
                float d = t - p;
                term = d * d;
            }
            acc += term;
        }
    }

    // 4) Deterministic block reduction
    for (int off = 32; off; off >>= 1)
        acc += __shfl_down(acc, off, 64);
    if ((tid & 63) == 0) sRed[tid >> 6] = acc;
    __syncthreads();
    if (tid == 0)
        partial[blockIdx.x] = sRed[0] + sRed[1] + sRed[2] + sRed[3];
}

__global__ __launch_bounds__(256) void yolo_reduce(
    const float* __restrict__ partial, int n, float* __restrict__ out, int B)
{
    __shared__ double s[256];
    const float4* p4 = (const float4*)partial;
    const int n4 = n >> 2;
    double a = 0.0;
    for (int j = threadIdx.x; j < n4; j += 256) {
        float4 v = p4[j];
        a += (double)v.x + (double)v.y + (double)v.z + (double)v.w;
    }
    for (int j = (n4 << 2) + threadIdx.x; j < n; j += 256)
        a += (double)partial[j];
    s[threadIdx.x] = a;
    __syncthreads();
    for (int str = 128; str; str >>= 1) {
        if (threadIdx.x < str) s[threadIdx.x] += s[threadIdx.x + str];
        __syncthreads();
    }
    if (threadIdx.x == 0) out[0] = (float)(s[0] / (double)B);
}

extern "C" void kernel_launch(void* const* d_in, const int* in_sizes, int n_in,
                              void* d_out, int out_size, void* d_ws, size_t ws_size,
                              hipStream_t stream) {
    const float* pred = (const float*)d_in[0];
    const float* bbox = (const float*)d_in[1];
    int B = in_sizes[0] / CELLSZ;
    int nbox = in_sizes[1] / (B * 5);
    if (nbox > MAXBOX) nbox = MAXBOX;
    float* out = (float*)d_out;
    float* partial = (float*)d_ws;

    int nblocks = (B + BPB - 1) / BPB;
    yolo_main<<<nblocks, 256, 0, stream>>>(pred, bbox, partial, B, nbox);
    yolo_reduce<<<1, 256, 0, stream>>>(partial, nblocks, out, B);
}